// Round 1
// baseline (1645.023 us; speedup 1.0000x reference)
//
#include <hip/hip_runtime.h>

namespace {
constexpr int kB = 16;
constexpr int kN = 8732;
constexpr int kC = 20;
constexpr int kRow = 25;      // 1 + C + 4
constexpr int kKeep = 300;    // NNS_K
constexpr int kTot = 200;     // K_TOTAL
constexpr float kConf = 0.01f;
// fl32(inter/union) > 0.45f  <=>  inter/union > 0.45f + ulp/2 (0.45f mantissa even,
// tie rounds to even i.e. down). M = (15099494*2 + 1) * 2^-26 exactly:
constexpr double kThr = 0.45000000298023223876953125;

constexpr int TPB1 = 512;
constexpr int EPT1 = 18;      // 512*18 = 9216 >= 8732
constexpr int NW1 = TPB1 / 64;

constexpr int TPB2 = 256;
constexpr int EPT2 = 24;      // 256*24 = 6144 >= 6000
constexpr int NW2 = TPB2 / 64;
}

// One block per (b, c) task: iterative-argmax greedy NMS (exactly equivalent to
// the reference's stable-sorted sequential scan, including min-index tie-break).
__global__ __launch_bounds__(TPB1, 2) void nms_kernel(const float* __restrict__ in,
                                                      float* __restrict__ ws_s,
                                                      float* __restrict__ ws_b) {
  const int task = blockIdx.x;
  const int b = task / kC;
  const int c = task - b * kC;
  const int tid = threadIdx.x;
  const int lane = tid & 63;
  const int wid = tid >> 6;

  const float* __restrict__ base = in + (size_t)b * kN * kRow;

  float sc[EPT1], by1[EPT1], bx1[EPT1], by2[EPT1], bx2[EPT1], bar[EPT1];
#pragma unroll
  for (int k = 0; k < EPT1; ++k) {
    const int n = tid + k * TPB1;
    if (n < kN) {
      const float* r = base + (size_t)n * kRow;
      const float s = r[1 + c];
      by1[k] = r[21]; bx1[k] = r[22]; by2[k] = r[23]; bx2[k] = r[24];
      // area exactly as reference: (y2-y1)*(x2-x1), f32 rn, no contraction
      bar[k] = __fmul_rn(__fsub_rn(by2[k], by1[k]), __fsub_rn(bx2[k], bx1[k]));
      sc[k] = (s > kConf) ? s : -1.0f;
    } else {
      by1[k] = bx1[k] = by2[k] = bx2[k] = bar[k] = 0.0f;
      sc[k] = -1.0f;
    }
  }

  __shared__ float s_wmax[NW1];
  __shared__ float s_box[5];   // y1,x1,y2,x2,area of newly selected
  __shared__ unsigned s_min;

  float lmax = -1.0f;
#pragma unroll
  for (int k = 0; k < EPT1; ++k) lmax = fmaxf(lmax, sc[k]);

  float* __restrict__ out_s = ws_s + (size_t)task * kKeep;
  float* __restrict__ out_b = ws_b + (size_t)task * kKeep * 4;

  int cnt = 0;
  while (cnt < kKeep) {
    // block-wide max of lmax
    float wm = lmax;
#pragma unroll
    for (int o = 32; o; o >>= 1) wm = fmaxf(wm, __shfl_xor(wm, o));
    if (lane == 0) s_wmax[wid] = wm;
    if (tid == 0) s_min = 0xFFFFFFFFu;
    __syncthreads();  // B1
    float smax = s_wmax[0];
#pragma unroll
    for (int w = 1; w < NW1; ++w) smax = fmaxf(smax, s_wmax[w]);
    if (smax <= 0.0f) break;  // uniform: no active candidates remain
    // min original index among score==smax (matches stable argsort tie-break)
    if (lmax == smax) {
      unsigned mymin = 0xFFFFFFFFu;
#pragma unroll
      for (int k = EPT1 - 1; k >= 0; --k)
        if (sc[k] == smax) mymin = (unsigned)(tid + k * TPB1);
      atomicMin(&s_min, mymin);
    }
    __syncthreads();  // B2
    const unsigned sel = s_min;
    if ((sel % TPB1) == (unsigned)tid) {
#pragma unroll
      for (int k = 0; k < EPT1; ++k) {
        if ((unsigned)(tid + k * TPB1) == sel) {
          s_box[0] = by1[k]; s_box[1] = bx1[k];
          s_box[2] = by2[k]; s_box[3] = bx2[k];
          s_box[4] = bar[k];
          sc[k] = -1.0f;  // remove selected from candidate set
          out_s[cnt] = smax;
          out_b[cnt * 4 + 0] = by1[k];
          out_b[cnt * 4 + 1] = bx1[k];
          out_b[cnt * 4 + 2] = by2[k];
          out_b[cnt * 4 + 3] = bx2[k];
        }
      }
    }
    __syncthreads();  // B3
    const float sy1 = s_box[0], sx1 = s_box[1], sy2 = s_box[2], sx2 = s_box[3],
                sar = s_box[4];
    lmax = -1.0f;
#pragma unroll
    for (int k = 0; k < EPT1; ++k) {
      const float ty1 = fmaxf(by1[k], sy1);
      const float tx1 = fmaxf(bx1[k], sx1);
      const float ty2 = fminf(by2[k], sy2);
      const float tx2 = fminf(bx2[k], sx2);
      const float dy = fmaxf(__fsub_rn(ty2, ty1), 0.0f);
      const float dx = fmaxf(__fsub_rn(tx2, tx1), 0.0f);
      const float inter = __fmul_rn(dy, dx);
      const float uni = __fsub_rn(__fadd_rn(sar, bar[k]), inter);
      // exact emulation of fl32(inter/uni) > 0.45f
      const bool supp = (uni > 0.0f) && ((double)inter > kThr * (double)uni);
      sc[k] = supp ? -1.0f : sc[k];
      lmax = fmaxf(lmax, sc[k]);
    }
    ++cnt;
  }
  // mark unused slots empty (boxes in empty slots are never read when score<0)
  for (int s = cnt + tid; s < kKeep; s += TPB1) out_s[s] = -1.0f;
}

// One block per batch: stable top-200 (descending score, min flat-index ties),
// mirroring jax.lax.top_k + output formatting.
__global__ __launch_bounds__(TPB2) void topk_kernel(const float* __restrict__ ws_s,
                                                    const float* __restrict__ ws_b,
                                                    float* __restrict__ out) {
  const int b = blockIdx.x;
  const int tid = threadIdx.x;
  const int lane = tid & 63;
  const int wid = tid >> 6;
  const float* __restrict__ ss = ws_s + (size_t)b * kC * kKeep;
  const float* __restrict__ bb = ws_b + (size_t)b * kC * kKeep * 4;
  float* __restrict__ ob = out + (size_t)b * kTot * 6;

  float sc[EPT2];
#pragma unroll
  for (int j = 0; j < EPT2; ++j) {
    const int f = tid + j * TPB2;
    sc[j] = (f < kC * kKeep) ? ss[f] : -2.0f;
  }

  __shared__ float s_wmax[NW2];
  __shared__ unsigned s_min;

  int r = 0;
  for (; r < kTot; ++r) {
    float lm = sc[0];
#pragma unroll
    for (int j = 1; j < EPT2; ++j) lm = fmaxf(lm, sc[j]);
    float wm = lm;
#pragma unroll
    for (int o = 32; o; o >>= 1) wm = fmaxf(wm, __shfl_xor(wm, o));
    if (lane == 0) s_wmax[wid] = wm;
    if (tid == 0) s_min = 0xFFFFFFFFu;
    __syncthreads();
    float smax = s_wmax[0];
#pragma unroll
    for (int w = 1; w < NW2; ++w) smax = fmaxf(smax, s_wmax[w]);
    if (smax <= 0.0f) break;  // rest of rows are invalid
    if (lm == smax) {
      unsigned mymin = 0xFFFFFFFFu;
#pragma unroll
      for (int j = EPT2 - 1; j >= 0; --j)
        if (sc[j] == smax) mymin = (unsigned)(tid + j * TPB2);
      atomicMin(&s_min, mymin);
    }
    __syncthreads();
    const unsigned sel = s_min;
    if ((sel % TPB2) == (unsigned)tid) {
#pragma unroll
      for (int j = 0; j < EPT2; ++j)
        if ((unsigned)(tid + j * TPB2) == sel) sc[j] = -2.0f;
    }
    if (tid == 0) {
      const int cls = sel / kKeep;  // 0..19
      ob[r * 6 + 0] = (float)(cls + 1);
      ob[r * 6 + 1] = smax;
      ob[r * 6 + 2] = fminf(fmaxf(bb[sel * 4 + 0], 0.0f), 1.0f);
      ob[r * 6 + 3] = fminf(fmaxf(bb[sel * 4 + 1], 0.0f), 1.0f);
      ob[r * 6 + 4] = fminf(fmaxf(bb[sel * 4 + 2], 0.0f), 1.0f);
      ob[r * 6 + 5] = fminf(fmaxf(bb[sel * 4 + 3], 0.0f), 1.0f);
    }
    __syncthreads();  // protect s_min reset of next iteration
  }
  // invalid rows: class = 0+1 = 1, score 0, boxes 0
  for (int idx = r * 6 + tid; idx < kTot * 6; idx += TPB2) {
    ob[idx] = ((idx % 6) == 0) ? 1.0f : 0.0f;
  }
}

extern "C" void kernel_launch(void* const* d_in, const int* in_sizes, int n_in,
                              void* d_out, int out_size, void* d_ws, size_t ws_size,
                              hipStream_t stream) {
  const float* in = (const float*)d_in[0];
  float* out = (float*)d_out;
  float* ws_s = (float*)d_ws;                           // 320*300 floats
  float* ws_b = ws_s + (size_t)kB * kC * kKeep;         // 320*300*4 floats
  nms_kernel<<<dim3(kB * kC), dim3(TPB1), 0, stream>>>(in, ws_s, ws_b);
  topk_kernel<<<dim3(kB), dim3(TPB2), 0, stream>>>(ws_s, ws_b, out);
}